// Round 1
// baseline (254.391 us; speedup 1.0000x reference)
//
#include <hip/hip_runtime.h>
#include <hip/hip_bf16.h>
#include <math.h>

#define B_ 2
#define T_ 2048
#define C_ 1024
#define H_ 16
// head dim = 64

typedef __bf16 bf16x8 __attribute__((ext_vector_type(8)));
typedef __bf16 bf16x4 __attribute__((ext_vector_type(4)));
typedef float f32x4 __attribute__((ext_vector_type(4)));

__device__ __forceinline__ void gload16(const void* g, void* l) {
    __builtin_amdgcn_global_load_lds(
        (const __attribute__((address_space(1))) void*)g,
        (__attribute__((address_space(3))) void*)l, 16, 0, 0);
}

__device__ __forceinline__ f32x4 mfma16(bf16x8 a, bf16x8 b, f32x4 c) {
    return __builtin_amdgcn_mfma_f32_16x16x32_bf16(a, b, c, 0, 0, 0);
}

// ---------------- fp32 -> bf16 cast, float4-vectorized ----------------
__global__ __launch_bounds__(256) void cast_bf16(const float* __restrict__ in,
                                                 __bf16* __restrict__ out, int n4) {
    int i = blockIdx.x * 256 + threadIdx.x;
    if (i >= n4) return;
    float4 v = ((const float4*)in)[i];
    bf16x4 o;
    o[0] = (__bf16)v.x; o[1] = (__bf16)v.y; o[2] = (__bf16)v.z; o[3] = (__bf16)v.w;
    ((bf16x4*)out)[i] = o;
}

// ---------------- NT GEMM: C[m,n] = sum_k A[m,k]*B[n,k] ----------------
// 128x128 tile, BK=64, 4 waves (2x2), each wave 64x64 via 4x4 frags of 16x16x32.
template <bool OUT_F32>
__global__ __launch_bounds__(256) void gemm_bt(const __bf16* __restrict__ A,
                                               const __bf16* __restrict__ Bw,
                                               void* __restrict__ Cp,
                                               int N, int K) {
    const int tid  = threadIdx.x;
    const int lane = tid & 63;
    const int w    = tid >> 6;
    const int wr = w >> 1, wc = w & 1;
    const int l15 = lane & 15, lg = lane >> 4;
    const int bm = blockIdx.y * 128, bn = blockIdx.x * 128;
    __shared__ __bf16 Asm[128 * 64];
    __shared__ __bf16 Bsm[128 * 64];
    f32x4 acc[4][4] = {};

    for (int kt = 0; kt < K; kt += 64) {
        if (kt) __syncthreads();              // prior-tile reads done before restage
#pragma unroll
        for (int it = 0; it < 4; ++it) {      // 32 KB staged: 8 x 16B per thread
            const int c = it * 256 + tid;
            const int row = c >> 3, cc = (c & 7) * 8;
            gload16(A  + (size_t)(bm + row) * K + kt + cc, Asm + c * 8);
            gload16(Bw + (size_t)(bn + row) * K + kt + cc, Bsm + c * 8);
        }
        __syncthreads();                      // drains vmcnt(0) then barrier
#pragma unroll
        for (int kk = 0; kk < 64; kk += 32) {
            bf16x8 af[4], bf[4];
#pragma unroll
            for (int i = 0; i < 4; ++i)
                af[i] = *(const bf16x8*)&Asm[(wr * 64 + i * 16 + l15) * 64 + kk + lg * 8];
#pragma unroll
            for (int j = 0; j < 4; ++j)
                bf[j] = *(const bf16x8*)&Bsm[(wc * 64 + j * 16 + l15) * 64 + kk + lg * 8];
#pragma unroll
            for (int i = 0; i < 4; ++i)
#pragma unroll
                for (int j = 0; j < 4; ++j)
                    acc[i][j] = mfma16(af[i], bf[j], acc[i][j]);
        }
    }
    // epilogue: C/D layout col = lane&15, row = (lane>>4)*4 + r   [m89-verified]
#pragma unroll
    for (int i = 0; i < 4; ++i)
#pragma unroll
        for (int j = 0; j < 4; ++j)
#pragma unroll
            for (int r = 0; r < 4; ++r) {
                const int row = bm + wr * 64 + i * 16 + lg * 4 + r;
                const int col = bn + wc * 64 + j * 16 + l15;
                if (OUT_F32)
                    ((float*)Cp)[(size_t)row * N + col] = acc[i][j][r];
                else
                    ((__bf16*)Cp)[(size_t)row * N + col] = (__bf16)acc[i][j][r];
            }
}

// ---------------- RoPE on q,k + scatter to [B,H,T,64] ----------------
// one thread per (b,t,h,d<32); pairs (d, d+32) share angle t * 10000^(-d/32)
__global__ __launch_bounds__(256) void rope_qk(const __bf16* __restrict__ qkv,
                                               __bf16* __restrict__ Qb,
                                               __bf16* __restrict__ Kb) {
    const int u = blockIdx.x * 256 + threadIdx.x;   // [0, B*T*H*32)
    const int d = u & 31;
    const int h = (u >> 5) & 15;
    const int t = (u >> 9) & (T_ - 1);
    const int b = u >> 20;
    const size_t row = (size_t)(b * T_ + t) * (3 * C_);
    const int col = h * 64 + d;
    // inv_freq = 10000^(-d/32) = exp(-d * ln(10000)/32)
    const float ang = (float)t * expf((float)d * -0.28782313662425572f);
    const float cv = cosf(ang), sv = sinf(ang);
    const float q1 = (float)qkv[row + col];
    const float q2 = (float)qkv[row + col + 32];
    const float k1 = (float)qkv[row + C_ + col];
    const float k2 = (float)qkv[row + C_ + col + 32];
    const size_t orow = ((size_t)(b * H_ + h) * T_ + t) * 64 + d;
    Qb[orow]      = (__bf16)(q1 * cv - q2 * sv);
    Qb[orow + 32] = (__bf16)(q2 * cv + q1 * sv);
    Kb[orow]      = (__bf16)(k1 * cv - k2 * sv);
    Kb[orow + 32] = (__bf16)(k2 * cv + k1 * sv);
}

// ---------------- V transpose: qkv v-region -> Vt[B,H,64,T] ----------------
__global__ __launch_bounds__(256) void v_transpose(const __bf16* __restrict__ qkv,
                                                   __bf16* __restrict__ Vt) {
    const int bh = blockIdx.y, tt = blockIdx.x;   // (b*16+h), t-tile of 64
    const int b = bh >> 4, h = bh & 15;
    __shared__ __bf16 lds[64 * 65];               // [d][t], pad 65
    const int c = threadIdx.x;
    {   // load 64(t) x 64(d) tile, coalesced rows
        const int tr = c >> 2, dc = (c & 3) * 16;
        const __bf16* src = qkv + ((size_t)(b * T_ + tt * 64 + tr)) * (3 * C_)
                          + 2 * C_ + h * 64 + dc;
        bf16x8 v0 = *(const bf16x8*)src;
        bf16x8 v1 = *(const bf16x8*)(src + 8);
#pragma unroll
        for (int e = 0; e < 8; ++e) lds[(dc + e) * 65 + tr]     = v0[e];
#pragma unroll
        for (int e = 0; e < 8; ++e) lds[(dc + 8 + e) * 65 + tr] = v1[e];
    }
    __syncthreads();
    {   // store transposed rows, coalesced along t
        const int d = c >> 2, tc = (c & 3) * 16;
        bf16x8 o0, o1;
#pragma unroll
        for (int e = 0; e < 8; ++e) o0[e] = lds[d * 65 + tc + e];
#pragma unroll
        for (int e = 0; e < 8; ++e) o1[e] = lds[d * 65 + tc + 8 + e];
        __bf16* dst = Vt + ((size_t)bh * 64 + d) * T_ + tt * 64 + tc;
        *(bf16x8*)dst = o0;
        *(bf16x8*)(dst + 8) = o1;
    }
}

// ---------------- causal flash attention ----------------
// grid: x = q-tile (T/64, reversed so longest blocks launch first), y = b*H+h
// 4 waves x 16 q-rows; KVBLK=64; online softmax; P via LDS for MFMA-A layout.
__global__ __launch_bounds__(256) void attn_fwd(const __bf16* __restrict__ Qb,
                                                const __bf16* __restrict__ Kb,
                                                const __bf16* __restrict__ Vt,
                                                __bf16* __restrict__ Yatt) {
    const int bh = blockIdx.y;
    const int b = bh >> 4, h = bh & 15;
    const int qt = gridDim.x - 1 - blockIdx.x;
    const int tid = threadIdx.x, lane = tid & 63, w = tid >> 6;
    const int l15 = lane & 15, lg = lane >> 4;
    __shared__ __bf16 Ksm[64 * 64];       // [kv][d]
    __shared__ __bf16 Vsm[64 * 64];       // [d][kv]  (from pre-transposed Vt)
    __shared__ __bf16 Psm[4][16 * 64];    // per-wave [q][kv]

    const __bf16* Qp = Qb + ((size_t)bh * T_ + qt * 64) * 64;
    const __bf16* Kp = Kb + (size_t)bh * T_ * 64;
    const __bf16* Vp = Vt + (size_t)bh * 64 * T_;

    // Q fragments (A-layout: row = lane&15, k = (lane>>4)*8 .. +8)
    bf16x8 aq[2];
    aq[0] = *(const bf16x8*)&Qp[(w * 16 + l15) * 64 + lg * 8];
    aq[1] = *(const bf16x8*)&Qp[(w * 16 + l15) * 64 + 32 + lg * 8];

    f32x4 o[4] = {};
    float m_run[4], l_run[4];
#pragma unroll
    for (int r = 0; r < 4; ++r) { m_run[r] = -3.0e38f; l_run[r] = 0.f; }

    const int ntiles = qt + 1;
    for (int j = 0; j < ntiles; ++j) {
        __syncthreads();                  // prior PV reads done before restage
#pragma unroll
        for (int it = 0; it < 2; ++it) {  // stage K (8KB) + V^T (8KB)
            const int c = it * 256 + tid;
            const int row = c >> 3, cc = (c & 7) * 8;
            gload16(Kp + (size_t)(j * 64 + row) * 64 + cc, Ksm + c * 8);
            gload16(Vp + (size_t)row * T_ + j * 64 + cc,   Vsm + c * 8);
        }
        __syncthreads();

        // S = Q K^T  (16 q-rows x 64 kv-cols per wave)
        f32x4 s[4] = {};
#pragma unroll
        for (int cc = 0; cc < 4; ++cc) {
            bf16x8 bk0 = *(const bf16x8*)&Ksm[(cc * 16 + l15) * 64 + lg * 8];
            bf16x8 bk1 = *(const bf16x8*)&Ksm[(cc * 16 + l15) * 64 + 32 + lg * 8];
            s[cc] = mfma16(aq[0], bk0, s[cc]);
            s[cc] = mfma16(aq[1], bk1, s[cc]);
        }
        const bool diag = (j == qt);
#pragma unroll
        for (int cc = 0; cc < 4; ++cc)
#pragma unroll
            for (int r = 0; r < 4; ++r) {
                float v = s[cc][r] * 0.125f;   // 1/sqrt(64)
                if (diag && (cc * 16 + l15 > w * 16 + lg * 4 + r)) v = -3.0e38f;
                s[cc][r] = v;
            }
        // online softmax; row r lives on the 16 lanes sharing lane>>4
#pragma unroll
        for (int r = 0; r < 4; ++r) {
            float mx = fmaxf(fmaxf(s[0][r], s[1][r]), fmaxf(s[2][r], s[3][r]));
            mx = fmaxf(mx, __shfl_xor(mx, 1));
            mx = fmaxf(mx, __shfl_xor(mx, 2));
            mx = fmaxf(mx, __shfl_xor(mx, 4));
            mx = fmaxf(mx, __shfl_xor(mx, 8));
            const float mnew = fmaxf(m_run[r], mx);
            const float corr = expf(m_run[r] - mnew);
            m_run[r] = mnew;
            float rs = 0.f;
#pragma unroll
            for (int cc = 0; cc < 4; ++cc) {
                float p = expf(s[cc][r] - mnew);
                s[cc][r] = p;
                rs += p;
            }
            rs += __shfl_xor(rs, 1);
            rs += __shfl_xor(rs, 2);
            rs += __shfl_xor(rs, 4);
            rs += __shfl_xor(rs, 8);
            l_run[r] = l_run[r] * corr + rs;
#pragma unroll
            for (int n = 0; n < 4; ++n) o[n][r] *= corr;
#pragma unroll
            for (int cc = 0; cc < 4; ++cc)
                Psm[w][(lg * 4 + r) * 64 + cc * 16 + l15] = (__bf16)s[cc][r];
        }
        __syncthreads();                  // P visible (safe form)
        // O += P V   (A = P from LDS, B = V^T rows contiguous in kv)
#pragma unroll
        for (int kk = 0; kk < 2; ++kk) {
            bf16x8 ap = *(const bf16x8*)&Psm[w][l15 * 64 + kk * 32 + lg * 8];
#pragma unroll
            for (int n = 0; n < 4; ++n) {
                bf16x8 bv = *(const bf16x8*)&Vsm[(n * 16 + l15) * 64 + kk * 32 + lg * 8];
                o[n] = mfma16(ap, bv, o[n]);
            }
        }
    }
    // epilogue -> Yatt[b*T+t][h*64+d] bf16
#pragma unroll
    for (int n = 0; n < 4; ++n)
#pragma unroll
        for (int r = 0; r < 4; ++r) {
            const int t = qt * 64 + w * 16 + lg * 4 + r;
            const int col = h * 64 + n * 16 + l15;
            Yatt[(size_t)(b * T_ + t) * C_ + col] = (__bf16)(o[n][r] / l_run[r]);
        }
}

extern "C" void kernel_launch(void* const* d_in, const int* in_sizes, int n_in,
                              void* d_out, int out_size, void* d_ws, size_t ws_size,
                              hipStream_t stream) {
    const float* x      = (const float*)d_in[0];
    const float* w_attn = (const float*)d_in[1];
    const float* w_proj = (const float*)d_in[2];
    float* out = (float*)d_out;
    char* ws = (char*)d_ws;

    // workspace layout (bytes)
    __bf16* xb   = (__bf16*)(ws);              //  8.39 MB  x bf16
    __bf16* wab  = (__bf16*)(ws + 8388608);    //  6.29 MB  w_attn bf16
    __bf16* wpb  = (__bf16*)(ws + 14680064);   //  2.10 MB  w_proj bf16
    __bf16* qkvb = (__bf16*)(ws + 16777216);   // 25.17 MB  qkv bf16 [4096,3072]
    __bf16* Qb   = (__bf16*)(ws + 41943040);   //  8.39 MB  [B,H,T,64] roped
    __bf16* Kb   = (__bf16*)(ws + 50331648);   //  8.39 MB  [B,H,T,64] roped
    __bf16* Vt   = (__bf16*)(ws + 58720256);   //  8.39 MB  [B,H,64,T]
    __bf16* Ya   = (__bf16*)(ws + 67108864);   //  8.39 MB  attn out [4096,1024]

    const int nx  = B_ * T_ * C_;      // 4194304
    const int nwa = 3 * C_ * C_;       // 3145728
    const int nwp = C_ * C_;           // 1048576

    cast_bf16<<<dim3(nx  / 4 / 256), 256, 0, stream>>>(x,      xb,  nx  / 4);
    cast_bf16<<<dim3(nwa / 4 / 256), 256, 0, stream>>>(w_attn, wab, nwa / 4);
    cast_bf16<<<dim3(nwp / 4 / 256), 256, 0, stream>>>(w_proj, wpb, nwp / 4);

    // qkv = x @ w_attn^T  (M=4096, N=3072, K=1024), bf16 out
    gemm_bt<false><<<dim3(3 * C_ / 128, B_ * T_ / 128), 256, 0, stream>>>(
        xb, wab, (void*)qkvb, 3 * C_, C_);

    rope_qk<<<dim3((B_ * T_ * H_ * 32) / 256), 256, 0, stream>>>(qkvb, Qb, Kb);
    v_transpose<<<dim3(T_ / 64, B_ * H_), 256, 0, stream>>>(qkvb, Vt);

    attn_fwd<<<dim3(T_ / 64, B_ * H_), 256, 0, stream>>>(Qb, Kb, Vt, Ya);

    // y = att_out @ w_proj^T  (M=4096, N=1024, K=1024), fp32 out
    gemm_bt<true><<<dim3(C_ / 128, B_ * T_ / 128), 256, 0, stream>>>(
        Ya, wpb, (void*)out, C_, C_);
}

// Round 2
// 132.584 us; speedup vs baseline: 1.9187x; 1.9187x over previous
//
#include <hip/hip_runtime.h>
#include <hip/hip_bf16.h>
#include <math.h>

#define B_ 2
#define T_ 2048
#define C_ 1024
#define H_ 16
// head dim = 64

typedef __bf16 bf16x8 __attribute__((ext_vector_type(8)));
typedef __bf16 bf16x4 __attribute__((ext_vector_type(4)));
typedef float f32x4 __attribute__((ext_vector_type(4)));
typedef float f32x16 __attribute__((ext_vector_type(16)));
typedef unsigned int u32;

#if __has_builtin(__builtin_amdgcn_exp2f)
#define EXP2(x) __builtin_amdgcn_exp2f(x)
#else
#define EXP2(x) exp2f(x)
#endif

__device__ __forceinline__ void gload16(const void* g, void* l) {
    __builtin_amdgcn_global_load_lds(
        (const __attribute__((address_space(1))) void*)g,
        (__attribute__((address_space(3))) void*)l, 16, 0, 0);
}

__device__ __forceinline__ f32x4 mfma16(bf16x8 a, bf16x8 b, f32x4 c) {
    return __builtin_amdgcn_mfma_f32_16x16x32_bf16(a, b, c, 0, 0, 0);
}
__device__ __forceinline__ f32x16 mfma32(bf16x8 a, bf16x8 b, f32x16 c) {
    return __builtin_amdgcn_mfma_f32_32x32x16_bf16(a, b, c, 0, 0, 0);
}

__device__ __forceinline__ u32 cvtpk(float lo, float hi) {
    u32 r;
    asm("v_cvt_pk_bf16_f32 %0, %1, %2" : "=v"(r) : "v"(lo), "v"(hi));
    return r;
}

__device__ __forceinline__ void plane32swap(u32& a, u32& b) {
#if __has_builtin(__builtin_amdgcn_permlane32_swap)
    auto r = __builtin_amdgcn_permlane32_swap(a, b, false, false);
    a = r[0]; b = r[1];
#else
    asm("v_permlane32_swap_b32 %0, %1" : "+v"(a), "+v"(b));
#endif
}

// ---------------- fp32 -> bf16 cast, float4-vectorized ----------------
__global__ __launch_bounds__(256) void cast_bf16(const float* __restrict__ in,
                                                 __bf16* __restrict__ out, int n4) {
    int i = blockIdx.x * 256 + threadIdx.x;
    if (i >= n4) return;
    float4 v = ((const float4*)in)[i];
    bf16x4 o;
    o[0] = (__bf16)v.x; o[1] = (__bf16)v.y; o[2] = (__bf16)v.z; o[3] = (__bf16)v.w;
    ((bf16x4*)out)[i] = o;
}

// ---------------- NT GEMM: C[m,n] = sum_k A[m,k]*B[n,k] ----------------
template <bool OUT_F32>
__global__ __launch_bounds__(256) void gemm_bt(const __bf16* __restrict__ A,
                                               const __bf16* __restrict__ Bw,
                                               void* __restrict__ Cp,
                                               int N, int K) {
    const int tid  = threadIdx.x;
    const int lane = tid & 63;
    const int w    = tid >> 6;
    const int wr = w >> 1, wc = w & 1;
    const int l15 = lane & 15, lg = lane >> 4;
    const int bm = blockIdx.y * 128, bn = blockIdx.x * 128;
    __shared__ __bf16 Asm[128 * 64];
    __shared__ __bf16 Bsm[128 * 64];
    f32x4 acc[4][4] = {};

    for (int kt = 0; kt < K; kt += 64) {
        if (kt) __syncthreads();
#pragma unroll
        for (int it = 0; it < 4; ++it) {
            const int c = it * 256 + tid;
            const int row = c >> 3, cc = (c & 7) * 8;
            gload16(A  + (size_t)(bm + row) * K + kt + cc, Asm + c * 8);
            gload16(Bw + (size_t)(bn + row) * K + kt + cc, Bsm + c * 8);
        }
        __syncthreads();
#pragma unroll
        for (int kk = 0; kk < 64; kk += 32) {
            bf16x8 af[4], bf[4];
#pragma unroll
            for (int i = 0; i < 4; ++i)
                af[i] = *(const bf16x8*)&Asm[(wr * 64 + i * 16 + l15) * 64 + kk + lg * 8];
#pragma unroll
            for (int j = 0; j < 4; ++j)
                bf[j] = *(const bf16x8*)&Bsm[(wc * 64 + j * 16 + l15) * 64 + kk + lg * 8];
#pragma unroll
            for (int i = 0; i < 4; ++i)
#pragma unroll
                for (int j = 0; j < 4; ++j)
                    acc[i][j] = mfma16(af[i], bf[j], acc[i][j]);
        }
    }
#pragma unroll
    for (int i = 0; i < 4; ++i)
#pragma unroll
        for (int j = 0; j < 4; ++j)
#pragma unroll
            for (int r = 0; r < 4; ++r) {
                const int row = bm + wr * 64 + i * 16 + lg * 4 + r;
                const int col = bn + wc * 64 + j * 16 + l15;
                if (OUT_F32)
                    ((float*)Cp)[(size_t)row * N + col] = acc[i][j][r];
                else
                    ((__bf16*)Cp)[(size_t)row * N + col] = (__bf16)acc[i][j][r];
            }
}

// ---------------- RoPE on q,k + scatter to [B,H,T,64] ----------------
__global__ __launch_bounds__(256) void rope_qk(const __bf16* __restrict__ qkv,
                                               __bf16* __restrict__ Qb,
                                               __bf16* __restrict__ Kb) {
    const int u = blockIdx.x * 256 + threadIdx.x;
    const int d = u & 31;
    const int h = (u >> 5) & 15;
    const int t = (u >> 9) & (T_ - 1);
    const int b = u >> 20;
    const size_t row = (size_t)(b * T_ + t) * (3 * C_);
    const int col = h * 64 + d;
    const float ang = (float)t * expf((float)d * -0.28782313662425572f);
    const float cv = cosf(ang), sv = sinf(ang);
    const float q1 = (float)qkv[row + col];
    const float q2 = (float)qkv[row + col + 32];
    const float k1 = (float)qkv[row + C_ + col];
    const float k2 = (float)qkv[row + C_ + col + 32];
    const size_t orow = ((size_t)(b * H_ + h) * T_ + t) * 64 + d;
    Qb[orow]      = (__bf16)(q1 * cv - q2 * sv);
    Qb[orow + 32] = (__bf16)(q2 * cv + q1 * sv);
    Kb[orow]      = (__bf16)(k1 * cv - k2 * sv);
    Kb[orow + 32] = (__bf16)(k2 * cv + k1 * sv);
}

// ---------------- V transpose: qkv v-region -> Vt[B,H,64,T] ----------------
__global__ __launch_bounds__(256) void v_transpose(const __bf16* __restrict__ qkv,
                                                   __bf16* __restrict__ Vt) {
    const int bh = blockIdx.y, tt = blockIdx.x;
    const int b = bh >> 4, h = bh & 15;
    __shared__ __bf16 lds[64 * 65];
    const int c = threadIdx.x;
    {
        const int tr = c >> 2, dc = (c & 3) * 16;
        const __bf16* src = qkv + ((size_t)(b * T_ + tt * 64 + tr)) * (3 * C_)
                          + 2 * C_ + h * 64 + dc;
        bf16x8 v0 = *(const bf16x8*)src;
        bf16x8 v1 = *(const bf16x8*)(src + 8);
#pragma unroll
        for (int e = 0; e < 8; ++e) lds[(dc + e) * 65 + tr]     = v0[e];
#pragma unroll
        for (int e = 0; e < 8; ++e) lds[(dc + 8 + e) * 65 + tr] = v1[e];
    }
    __syncthreads();
    {
        const int d = c >> 2, tc = (c & 3) * 16;
        bf16x8 o0, o1;
#pragma unroll
        for (int e = 0; e < 8; ++e) o0[e] = lds[d * 65 + tc + e];
#pragma unroll
        for (int e = 0; e < 8; ++e) o1[e] = lds[d * 65 + tc + 8 + e];
        __bf16* dst = Vt + ((size_t)bh * 64 + d) * T_ + tt * 64 + tc;
        *(bf16x8*)dst = o0;
        *(bf16x8*)(dst + 8) = o1;
    }
}

// ---------------- causal flash attention, swapped-operand 32x32 ----------------
// 4 waves x 32 q-rows (QBLK=128), KVBLK=64. S^T = mfma(K,Q) -> q lane-local.
// Softmax fully in-register (exp2 domain, defer-max). P -> PV B-operand via
// cvt_pk + permlane32_swap (no P LDS). O^T = mfma(V^T, P^T) keeps q = lane&31.
// K/V tiles in LDS with XOR swizzle (byte ^= (row&7)<<4), staged by
// global_load_lds with pre-swizzled source.
__global__ __launch_bounds__(256) void attn_fwd(const __bf16* __restrict__ Qb,
                                                const __bf16* __restrict__ Kb,
                                                const __bf16* __restrict__ Vt,
                                                __bf16* __restrict__ Yatt) {
    const int gid = blockIdx.x;
    const int bh = (gid & 7) * 4 + ((gid >> 3) & 3);   // same-bh blocks -> same XCD
    const int qt = 15 - (gid >> 5);                    // big (late) q-tiles first
    const int b = bh >> 4, h = bh & 15;
    const int tid = threadIdx.x, lane = tid & 63, w = tid >> 6;
    const int l31 = lane & 31, hi = lane >> 5;
    const int hi4 = hi * 4;
    __shared__ __bf16 Ksm[64 * 64];   // [kv][d], rows XOR-swizzled
    __shared__ __bf16 Vsm[64 * 64];   // [d][kv], rows XOR-swizzled

    const int Q0 = qt * 128 + w * 32;          // wave's first q row
    const int qg = Q0 + l31;                   // this lane's q row
    const __bf16* Qp = Qb + ((size_t)bh * T_ + Q0) * 64;
    const __bf16* Kp = Kb + (size_t)bh * T_ * 64;
    const __bf16* Vp = Vt + (size_t)bh * 64 * T_;

    // Q as B-operand: col=q=l31, k = hi*8+j within d-slice [16ds,16ds+16)
    bf16x8 qf[4];
#pragma unroll
    for (int ds = 0; ds < 4; ++ds)
        qf[ds] = *(const bf16x8*)&Qp[l31 * 64 + ds * 16 + hi * 8];

    f32x16 ot[2] = {};            // O^T: d = db*32 + crow(r,hi), q = l31
    float m_run = -1e30f, l_run = 0.f;
    const float SCL = 0.18033688011112042f;    // (1/sqrt(64)) * log2(e)

    const int jmax = 2 * (qt + 1);
    for (int j = 0; j < jmax; ++j) {
        __syncthreads();                       // all waves done reading prev tile
#pragma unroll
        for (int it = 0; it < 2; ++it) {       // stage K (8KB) + V^T (8KB)
            const int g = it * 256 + tid;      // granule id (16B units)
            const int row = g >> 3;
            const int sg = (g & 7) ^ (row & 7);  // pre-swizzled source granule
            gload16(Kp + ((size_t)(j * 64 + row)) * 64 + sg * 8, Ksm + g * 8);
            gload16(Vp + (size_t)row * T_ + j * 64 + sg * 8,     Vsm + g * 8);
        }
        __syncthreads();                       // drains vmcnt(0), tile ready

        if (j * 64 <= Q0 + 31) {               // wave-uniform: tile not fully masked
            // ---- S^T = K @ Q^T : lane holds q=l31, kv = a*32+crow(r,hi) ----
            f32x16 st[2] = {};
#pragma unroll
            for (int a = 0; a < 2; ++a)
#pragma unroll
                for (int ds = 0; ds < 4; ++ds) {
                    const int row = a * 32 + l31;
                    const int off = (ds * 32 + hi * 16) ^ ((row & 7) << 4);
                    bf16x8 kf = *(const bf16x8*)((const char*)Ksm + row * 128 + off);
                    st[a] = mfma32(kf, qf[ds], st[a]);
                }
            // ---- scale to exp2 domain + causal mask ----
            const bool needmask = (j * 64 + 63 > Q0);
            if (needmask) {
#pragma unroll
                for (int a = 0; a < 2; ++a)
#pragma unroll
                    for (int r = 0; r < 16; ++r) {
                        const int kv = j * 64 + a * 32 + (r & 3) + 8 * (r >> 2) + hi4;
                        st[a][r] = (kv > qg) ? -1e30f : st[a][r] * SCL;
                    }
            } else {
#pragma unroll
                for (int a = 0; a < 2; ++a)
#pragma unroll
                    for (int r = 0; r < 16; ++r) st[a][r] *= SCL;
            }
            // ---- in-lane max tree + one cross-half shuffle ----
            float t[8];
#pragma unroll
            for (int i = 0; i < 8; ++i)
                t[i] = fmaxf(fmaxf(st[0][i], st[0][i + 8]),
                             fmaxf(st[1][i], st[1][i + 8]));
            float mx = fmaxf(fmaxf(fmaxf(t[0], t[1]), fmaxf(t[2], t[3])),
                             fmaxf(fmaxf(t[4], t[5]), fmaxf(t[6], t[7])));
            mx = fmaxf(mx, __shfl_xor(mx, 32));
            // ---- defer-max (T13): rescale only when max moved > 10 (exp2 dom) ----
            if (!__all(mx - m_run <= 10.f)) {
                const float mnew = fmaxf(m_run, mx);
                const float corr = EXP2(m_run - mnew);
                l_run *= corr;
#pragma unroll
                for (int db = 0; db < 2; ++db)
#pragma unroll
                    for (int r = 0; r < 16; ++r) ot[db][r] *= corr;
                m_run = mnew;
            }
            // ---- p = exp2(s - m), in place; row-sum ----
            float s0 = 0.f, s1 = 0.f;
#pragma unroll
            for (int a = 0; a < 2; ++a)
#pragma unroll
                for (int r = 0; r < 16; ++r) {
                    const float e = EXP2(st[a][r] - m_run);
                    st[a][r] = e;
                    if (r & 1) s1 += e; else s0 += e;
                }
            float rs = s0 + s1;
            rs += __shfl_xor(rs, 32);
            l_run += rs;
            // ---- P^T -> B-operand frags: cvt_pk pairs + permlane32_swap ----
            bf16x8 pa[4];
#pragma unroll
            for (int ks = 0; ks < 4; ++ks) {
                const int a = ks >> 1, rb = (ks & 1) * 8;
                u32 X0 = cvtpk(st[a][rb + 0], st[a][rb + 1]);
                u32 X1 = cvtpk(st[a][rb + 2], st[a][rb + 3]);
                u32 Y0 = cvtpk(st[a][rb + 4], st[a][rb + 5]);
                u32 Y1 = cvtpk(st[a][rb + 6], st[a][rb + 7]);
                plane32swap(X0, Y0);
                plane32swap(X1, Y1);
                u32 dw[4] = {X0, X1, Y0, Y1};
                pa[ks] = *(bf16x8*)dw;
            }
            // ---- O^T += V^T-as-A @ P^T-as-B ----
#pragma unroll
            for (int ks = 0; ks < 4; ++ks)
#pragma unroll
                for (int db = 0; db < 2; ++db) {
                    const int row = db * 32 + l31;
                    const int off = (ks * 32 + hi * 16) ^ ((row & 7) << 4);
                    bf16x8 vf = *(const bf16x8*)((const char*)Vsm + row * 128 + off);
                    ot[db] = mfma32(vf, pa[ks], ot[db]);
                }
        }
    }
    // ---- epilogue: lane holds O^T (q = l31); normalize, pack, store 4B ----
    const float inv = 1.f / l_run;
    __bf16* Yp = Yatt + ((size_t)(b * T_ + qg)) * C_ + h * 64;
#pragma unroll
    for (int db = 0; db < 2; ++db)
#pragma unroll
        for (int rp = 0; rp < 8; ++rp) {
            const int r = rp * 2;
            const u32 pk = cvtpk(ot[db][r] * inv, ot[db][r + 1] * inv);
            const int d = db * 32 + (r & 3) + 8 * (r >> 2) + hi4;
            *(u32*)&Yp[d] = pk;
        }
}

extern "C" void kernel_launch(void* const* d_in, const int* in_sizes, int n_in,
                              void* d_out, int out_size, void* d_ws, size_t ws_size,
                              hipStream_t stream) {
    const float* x      = (const float*)d_in[0];
    const float* w_attn = (const float*)d_in[1];
    const float* w_proj = (const float*)d_in[2];
    float* out = (float*)d_out;
    char* ws = (char*)d_ws;

    __bf16* xb   = (__bf16*)(ws);
    __bf16* wab  = (__bf16*)(ws + 8388608);
    __bf16* wpb  = (__bf16*)(ws + 14680064);
    __bf16* qkvb = (__bf16*)(ws + 16777216);
    __bf16* Qb   = (__bf16*)(ws + 41943040);
    __bf16* Kb   = (__bf16*)(ws + 50331648);
    __bf16* Vt   = (__bf16*)(ws + 58720256);
    __bf16* Ya   = (__bf16*)(ws + 67108864);

    const int nx  = B_ * T_ * C_;
    const int nwa = 3 * C_ * C_;
    const int nwp = C_ * C_;

    cast_bf16<<<dim3(nx  / 4 / 256), 256, 0, stream>>>(x,      xb,  nx  / 4);
    cast_bf16<<<dim3(nwa / 4 / 256), 256, 0, stream>>>(w_attn, wab, nwa / 4);
    cast_bf16<<<dim3(nwp / 4 / 256), 256, 0, stream>>>(w_proj, wpb, nwp / 4);

    gemm_bt<false><<<dim3(3 * C_ / 128, B_ * T_ / 128), 256, 0, stream>>>(
        xb, wab, (void*)qkvb, 3 * C_, C_);

    rope_qk<<<dim3((B_ * T_ * H_ * 32) / 256), 256, 0, stream>>>(qkvb, Qb, Kb);
    v_transpose<<<dim3(T_ / 64, B_ * H_), 256, 0, stream>>>(qkvb, Vt);

    attn_fwd<<<dim3(16 * 32), 256, 0, stream>>>(Qb, Kb, Vt, Ya);

    gemm_bt<true><<<dim3(C_ / 128, B_ * T_ / 128), 256, 0, stream>>>(
        Ya, wpb, (void*)out, C_, C_);
}